// Round 1
// baseline (415.317 us; speedup 1.0000x reference)
//
#include <hip/hip_runtime.h>
#include <math.h>

// EfficientDet post-processing, fully fused device pipeline.
// Stages: decode boxes -> transpose class scores to sortable keys ->
// per-class radix-select top-512 -> IoU-bitmask NMS -> global top-100.

#define A_N   110484
#define C_N   90
#define KCAND 512
#define NBINS 8192        // 13-bit histogram bins (key >> 19)
#define KSH   19
#define MAXDET 100
#define IMG_F 768.0f
#define THRESH 0.05f

typedef unsigned int u32;
typedef unsigned long long u64;

__device__ __forceinline__ u32 fkey(float f) {
    u32 u = __float_as_uint(f);
    return (u & 0x80000000u) ? ~u : (u | 0x80000000u);
}
__device__ __forceinline__ float unfkey(u32 k) {
    u32 u = (k & 0x80000000u) ? (k ^ 0x80000000u) : ~k;
    return __uint_as_float(u);
}

// ---------------- Stage 1: decode + clip all anchor boxes ----------------
__global__ void decode_kernel(const float* __restrict__ anchors,
                              const float* __restrict__ reg,
                              float4* __restrict__ boxes) {
    int a = blockIdx.x * blockDim.x + threadIdx.x;
    if (a >= A_N) return;
    float4 an = ((const float4*)anchors)[a];
    float4 dl = ((const float4*)reg)[a];
    float wa = an.z - an.x, ha = an.w - an.y;
    float cxa = an.x + 0.5f * wa, cya = an.y + 0.5f * ha;
    float cx = cxa + dl.x * wa;
    float cy = cya + dl.y * ha;
    float w = expf(dl.z) * wa;
    float h = expf(dl.w) * ha;
    float4 o;
    o.x = fminf(fmaxf(cx - 0.5f * w, 0.0f), IMG_F);
    o.y = fminf(fmaxf(cy - 0.5f * h, 0.0f), IMG_F);
    o.z = fminf(fmaxf(cx + 0.5f * w, 0.0f), IMG_F);
    o.w = fminf(fmaxf(cy + 0.5f * h, 0.0f), IMG_F);
    boxes[a] = o;
}

// ------- Stage 2: transpose (A,90) cls -> (90,A) sortable sigmoid keys -------
// Key = flipped-float of the float32 sigmoid score, so ordering (and float
// ties) match the reference's top_k on sigmoid values.
__global__ void transpose_kernel(const float* __restrict__ cls,
                                 u32* __restrict__ keysT) {
    __shared__ u32 tile[64 * C_N];   // 23 KB
    int a0 = blockIdx.x * 64;
    int lim = min(64, A_N - a0);
    int cnt = lim * C_N;
    const float* src = cls + (size_t)a0 * C_N;
    for (int i = threadIdx.x; i < cnt; i += blockDim.x) {
        float x = src[i];
        float s = 1.0f / (1.0f + expf(-x));
        tile[i] = fkey(s);
    }
    __syncthreads();
    for (int j = threadIdx.x; j < C_N * 64; j += blockDim.x) {
        int c = j >> 6, aa = j & 63;
        if (aa < lim)
            keysT[(size_t)c * A_N + a0 + aa] = tile[aa * C_N + c];
    }
}

// ---------------- Stage 3: per-class exact top-512 ----------------
__global__ __launch_bounds__(1024)
void select_kernel(const u32* __restrict__ keysT,
                   const float4* __restrict__ boxes,
                   float4* __restrict__ cand_boxes,
                   float* __restrict__ cand_scores) {
    __shared__ u32 hist[NBINS];     // 32 KB
    __shared__ u32 csum[1024];      // 4 KB
    __shared__ u64 buf[2048];       // 16 KB
    __shared__ int sP, sNsel;
    const int c = blockIdx.x, tid = threadIdx.x;
    const u32* keys = keysT + (size_t)c * A_N;

    for (int i = tid; i < NBINS; i += 1024) hist[i] = 0;
    if (tid == 0) sNsel = 0;
    __syncthreads();
    for (int i = tid; i < A_N; i += 1024)
        atomicAdd(&hist[keys[i] >> KSH], 1u);
    __syncthreads();
    {   // chunk sums over 8 bins/thread, descending bin order
        u32 s = 0; int hi = NBINS - 1 - 8 * tid;
        #pragma unroll
        for (int j = 0; j < 8; ++j) s += hist[hi - j];
        csum[tid] = s;
    }
    __syncthreads();
    if (tid == 0) {   // find pivot bin: cumulative-from-top crosses KCAND
        u32 cum = 0; int P = 0; bool found = false;
        for (int t = 0; t < 1024 && !found; ++t) {
            if (cum + csum[t] >= (u32)KCAND) {
                int hi = NBINS - 1 - 8 * t;
                for (int j = 0; j < 8; ++j) {
                    u32 h = hist[hi - j];
                    if (cum + h >= (u32)KCAND) { P = hi - j; found = true; break; }
                    cum += h;
                }
            } else cum += csum[t];
        }
        sP = found ? P : 0;
    }
    __syncthreads();
    const u32 P = (u32)sP;
    for (int i = tid; i < A_N; i += 1024) {
        u32 k = keys[i];
        if ((k >> KSH) >= P) {
            int p = atomicAdd(&sNsel, 1);
            if (p < 2048)
                buf[p] = (((u64)(~k)) << 32) | (u32)i;  // sort asc = score desc, idx asc
        }
    }
    __syncthreads();
    int n = min(sNsel, 2048);
    for (int i = tid; i < 2048; i += 1024) if (i >= n) buf[i] = ~0ULL;
    __syncthreads();
    // bitonic sort, N = 2048, ascending
    for (u32 kk = 2; kk <= 2048; kk <<= 1) {
        for (u32 j = kk >> 1; j > 0; j >>= 1) {
            for (u32 i = tid; i < 2048; i += 1024) {
                u32 ixj = i ^ j;
                if (ixj > i) {
                    u64 x = buf[i], y = buf[ixj];
                    bool up = ((i & kk) == 0);
                    if (up ? (x > y) : (x < y)) { buf[i] = y; buf[ixj] = x; }
                }
            }
            __syncthreads();
        }
    }
    if (tid < KCAND) {
        u64 comp = buf[tid];
        u32 idx = (u32)comp;
        u32 key = ~((u32)(comp >> 32));
        cand_scores[c * KCAND + tid] = unfkey(key);
        cand_boxes[c * KCAND + tid] = boxes[idx];
    }
}

// ---------------- Stage 4: IoU bitmask + sequential greedy NMS ----------------
__global__ __launch_bounds__(512)
void nms_kernel(const float4* __restrict__ cand_boxes,
                const float* __restrict__ cand_scores,
                float* __restrict__ kept) {
    __shared__ float4 bx[KCAND];       // 8 KB
    __shared__ float ar[KCAND];        // 2 KB
    __shared__ float sc[KCAND];        // 2 KB
    __shared__ u32 bmask[KCAND * 16];  // 32 KB
    const int c = blockIdx.x, i = threadIdx.x;
    float4 b = cand_boxes[c * KCAND + i];
    bx[i] = b;
    ar[i] = (b.z - b.x) * (b.w - b.y);
    sc[i] = cand_scores[c * KCAND + i];
    __syncthreads();
    const float ai = ar[i];
    u32 m[16];
    #pragma unroll
    for (int w = 0; w < 16; ++w) m[w] = 0;
    for (int j = 0; j < KCAND; ++j) {
        float4 bj = bx[j];
        float xx1 = fmaxf(b.x, bj.x), yy1 = fmaxf(b.y, bj.y);
        float xx2 = fminf(b.z, bj.z), yy2 = fminf(b.w, bj.w);
        float iw = fmaxf(xx2 - xx1, 0.0f), ih = fmaxf(yy2 - yy1, 0.0f);
        float inter = iw * ih;
        float uni = ai + ar[j] - inter + 1e-8f;
        if (inter > 0.5f * uni) m[j >> 5] |= (1u << (j & 31));
    }
    #pragma unroll
    for (int w = 0; w < 16; ++w) bmask[i * 16 + w] = m[w];
    __syncthreads();
    if (i < 64) {   // wave 0: sequential greedy scan on bitmasks
        u32 removed = 0;   // lane w<16 owns suppressed word w
        for (int t = 0; t < KCAND; ++t) {
            u32 rw = (u32)__shfl((int)removed, t >> 5);
            bool d = (sc[t] > THRESH) && (((rw >> (t & 31)) & 1u) == 0u);
            if (d && i < 16) removed |= bmask[t * 16 + i];
            if (i == 0) kept[c * KCAND + t] = d ? sc[t] : -1.0f;
        }
    }
}

// ---------------- Stage 5: global top-100 + emit detections ----------------
__global__ __launch_bounds__(1024)
void final_kernel(const float* __restrict__ kept,
                  const float4* __restrict__ cand_boxes,
                  float* __restrict__ out) {
    __shared__ u32 hist[NBINS];   // 32 KB
    __shared__ u32 csum[1024];
    __shared__ u64 buf[1024];     // 8 KB
    __shared__ int sP, sN;
    const int tid = threadIdx.x;
    const int TOT = C_N * KCAND;
    for (int i = tid; i < NBINS; i += 1024) hist[i] = 0;
    if (tid == 0) sN = 0;
    __syncthreads();
    for (int i = tid; i < TOT; i += 1024) {
        float s = kept[i];
        if (s > 0.0f) atomicAdd(&hist[fkey(s) >> KSH], 1u);
    }
    __syncthreads();
    {   u32 s = 0; int hi = NBINS - 1 - 8 * tid;
        #pragma unroll
        for (int j = 0; j < 8; ++j) s += hist[hi - j];
        csum[tid] = s;
    }
    __syncthreads();
    if (tid == 0) {
        u32 cum = 0; int P = 0; bool found = false;
        for (int t = 0; t < 1024 && !found; ++t) {
            if (cum + csum[t] >= (u32)MAXDET) {
                int hi = NBINS - 1 - 8 * t;
                for (int j = 0; j < 8; ++j) {
                    u32 h = hist[hi - j];
                    if (cum + h >= (u32)MAXDET) { P = hi - j; found = true; break; }
                    cum += h;
                }
            } else cum += csum[t];
        }
        sP = found ? P : 0;   // P=0 => fewer than 100 kept, take all
    }
    __syncthreads();
    const u32 P = (u32)sP;
    for (int i = tid; i < TOT; i += 1024) {
        float s = kept[i];
        if (s > 0.0f && (fkey(s) >> KSH) >= P) {
            int p = atomicAdd(&sN, 1);
            if (p < 1024)
                buf[p] = (((u64)(~fkey(s))) << 32) | (u32)i;
        }
    }
    __syncthreads();
    int n = min(sN, 1024);
    for (int i = tid; i < 1024; i += 1024) if (i >= n) buf[i] = ~0ULL;
    __syncthreads();
    for (u32 kk = 2; kk <= 1024; kk <<= 1) {
        for (u32 j = kk >> 1; j > 0; j >>= 1) {
            for (u32 i = tid; i < 1024; i += 1024) {
                u32 ixj = i ^ j;
                if (ixj > i) {
                    u64 x = buf[i], y = buf[ixj];
                    bool up = ((i & kk) == 0);
                    if (up ? (x > y) : (x < y)) { buf[i] = y; buf[ixj] = x; }
                }
            }
            __syncthreads();
        }
    }
    if (tid < MAXDET) {
        float row0 = 0, row1 = 0, row2 = 0, row3 = 0, row4 = 0, row5 = 0, row6 = 0;
        if (tid < n) {
            u64 comp = buf[tid];
            u32 flat = (u32)comp;
            u32 key = ~((u32)(comp >> 32));
            float s = unfkey(key);
            if (s > 0.0f) {
                float4 b = cand_boxes[flat];
                row1 = b.x; row2 = b.y; row3 = b.z; row4 = b.w;
                row5 = s; row6 = (float)(flat >> 9);   // flat / 512 = class label
            }
        }
        float* o = out + tid * 7;
        o[0] = row0; o[1] = row1; o[2] = row2; o[3] = row3;
        o[4] = row4; o[5] = row5; o[6] = row6;
    }
}

extern "C" void kernel_launch(void* const* d_in, const int* in_sizes, int n_in,
                              void* d_out, int out_size, void* d_ws, size_t ws_size,
                              hipStream_t stream) {
    const float* reg     = (const float*)d_in[1];
    const float* cls     = (const float*)d_in[2];
    const float* anchors = (const float*)d_in[3];
    float* out = (float*)d_out;

    char* ws = (char*)d_ws;
    size_t off = 0;
    auto alloc = [&](size_t bytes) -> void* {
        void* p = ws + off;
        off = (off + bytes + 255) & ~(size_t)255;
        return p;
    };
    u32*    keysT       = (u32*)   alloc((size_t)C_N * A_N * sizeof(u32));   // 39.8 MB
    float4* boxes       = (float4*)alloc((size_t)A_N * sizeof(float4));      // 1.77 MB
    float4* cand_boxes  = (float4*)alloc((size_t)C_N * KCAND * sizeof(float4));
    float*  cand_scores = (float*) alloc((size_t)C_N * KCAND * sizeof(float));
    float*  kept        = (float*) alloc((size_t)C_N * KCAND * sizeof(float));
    (void)ws_size;

    decode_kernel<<<(A_N + 255) / 256, 256, 0, stream>>>(anchors, reg, boxes);
    transpose_kernel<<<(A_N + 63) / 64, 256, 0, stream>>>(cls, keysT);
    select_kernel<<<C_N, 1024, 0, stream>>>(keysT, boxes, cand_boxes, cand_scores);
    nms_kernel<<<C_N, KCAND, 0, stream>>>(cand_boxes, cand_scores, kept);
    final_kernel<<<1, 1024, 0, stream>>>(kept, cand_boxes, out);
}

// Round 2
// 383.500 us; speedup vs baseline: 1.0830x; 1.0830x over previous
//
#include <hip/hip_runtime.h>
#include <math.h>

// EfficientDet post-processing, device pipeline v2.
// decode -> transpose(sigmoid->sortable key, padded LDS) ->
// sliced per-class histogram -> pivot -> sliced collect -> per-class sort ->
// IoU-bitmask NMS (upper-triangular) -> global top-100.

#define A_N   110484
#define C_N   90
#define KCAND 512
#define NBINS 8192        // 13-bit histogram bins (key >> 19)
#define KSH   19
#define MAXDET 100
#define IMG_F 768.0f
#define THRESH 0.05f
#define NSLICE 8
#define SLICE_LEN ((A_N + NSLICE - 1) / NSLICE)   // 13811
#define CAND_CAP 2048

typedef unsigned int u32;
typedef unsigned long long u64;

__device__ __forceinline__ u32 fkey(float f) {
    u32 u = __float_as_uint(f);
    return (u & 0x80000000u) ? ~u : (u | 0x80000000u);
}
__device__ __forceinline__ float unfkey(u32 k) {
    u32 u = (k & 0x80000000u) ? (k ^ 0x80000000u) : ~k;
    return __uint_as_float(u);
}

// ---------------- Stage 1: decode + clip all anchor boxes ----------------
__global__ void decode_kernel(const float* __restrict__ anchors,
                              const float* __restrict__ reg,
                              float4* __restrict__ boxes) {
    int a = blockIdx.x * blockDim.x + threadIdx.x;
    if (a >= A_N) return;
    float4 an = ((const float4*)anchors)[a];
    float4 dl = ((const float4*)reg)[a];
    float wa = an.z - an.x, ha = an.w - an.y;
    float cxa = an.x + 0.5f * wa, cya = an.y + 0.5f * ha;
    float cx = cxa + dl.x * wa;
    float cy = cya + dl.y * ha;
    float w = expf(dl.z) * wa;
    float h = expf(dl.w) * ha;
    float4 o;
    o.x = fminf(fmaxf(cx - 0.5f * w, 0.0f), IMG_F);
    o.y = fminf(fmaxf(cy - 0.5f * h, 0.0f), IMG_F);
    o.z = fminf(fmaxf(cx + 0.5f * w, 0.0f), IMG_F);
    o.w = fminf(fmaxf(cy + 0.5f * h, 0.0f), IMG_F);
    boxes[a] = o;
}

// ------- Stage 2: transpose (A,90) cls -> (90,A) sortable sigmoid keys -------
// LDS tile padded to stride 91 (odd) -> conflict-free strided reads.
__global__ void transpose_kernel(const float* __restrict__ cls,
                                 u32* __restrict__ keysT) {
    __shared__ u32 tile[64 * 91];   // 23.3 KB
    int a0 = blockIdx.x * 64;
    int lim = min(64, A_N - a0);
    int cnt = lim * C_N;
    const float* src = cls + (size_t)a0 * C_N;
    for (int i = threadIdx.x; i < cnt; i += blockDim.x) {
        float x = src[i];
        float s = 1.0f / (1.0f + expf(-x));
        u32 aa = (u32)i / C_N, c = (u32)i % C_N;   // magic-div by constant
        tile[aa * 91 + c] = fkey(s);
    }
    __syncthreads();
    for (int j = threadIdx.x; j < C_N * 64; j += blockDim.x) {
        int c = j >> 6, aa = j & 63;
        if (aa < lim)
            keysT[(size_t)c * A_N + a0 + aa] = tile[aa * 91 + c];
    }
}

// ---------------- Stage 3a: sliced per-class histogram ----------------
__global__ __launch_bounds__(256)
void hist_kernel(const u32* __restrict__ keysT, u32* __restrict__ ghist) {
    __shared__ u32 h[NBINS];   // 32 KB
    const int c = blockIdx.x / NSLICE, s = blockIdx.x % NSLICE;
    for (int i = threadIdx.x; i < NBINS; i += 256) h[i] = 0;
    __syncthreads();
    const int lo = s * SLICE_LEN, hiEnd = min(A_N, lo + SLICE_LEN);
    const u32* keys = keysT + (size_t)c * A_N;
    for (int i = lo + threadIdx.x; i < hiEnd; i += 256)
        atomicAdd(&h[keys[i] >> KSH], 1u);
    __syncthreads();
    u32* gh = ghist + (size_t)c * NBINS;
    for (int i = threadIdx.x; i < NBINS; i += 256) {
        u32 v = h[i];
        if (v) atomicAdd(&gh[i], v);
    }
}

// ---------------- Stage 3b: per-class pivot bin (top-512 crossing) ----------------
__global__ __launch_bounds__(256)
void pivot_kernel(const u32* __restrict__ ghist, u32* __restrict__ pivotP,
                  u32* __restrict__ cnt) {
    __shared__ u32 csum[256];
    const int c = blockIdx.x, tid = threadIdx.x;
    const u32* gh = ghist + (size_t)c * NBINS;
    u32 ssum = 0; const int hi = NBINS - 1 - 32 * tid;
    #pragma unroll 4
    for (int j = 0; j < 32; ++j) ssum += gh[hi - j];
    csum[tid] = ssum;
    __syncthreads();
    if (tid == 0) {
        u32 cum = 0, P = 0; bool found = false;
        for (int t = 0; t < 256 && !found; ++t) {
            if (cum + csum[t] >= (u32)KCAND) {
                int h2 = NBINS - 1 - 32 * t;
                for (int j = 0; j < 32; ++j) {
                    u32 hv = gh[h2 - j];
                    if (cum + hv >= (u32)KCAND) { P = (u32)(h2 - j); found = true; break; }
                    cum += hv;
                }
            } else cum += csum[t];
        }
        pivotP[c] = P;
        cnt[c] = 0;
    }
}

// ---------------- Stage 3c: sliced collect of candidates >= pivot ----------------
__global__ __launch_bounds__(256)
void collect_kernel(const u32* __restrict__ keysT, const u32* __restrict__ pivotP,
                    u32* __restrict__ cnt, u64* __restrict__ candbuf) {
    __shared__ u64 lbuf[CAND_CAP];   // 16 KB
    __shared__ int lcnt, gbase;
    const int c = blockIdx.x / NSLICE, s = blockIdx.x % NSLICE;
    if (threadIdx.x == 0) lcnt = 0;
    __syncthreads();
    const u32 P = pivotP[c];
    const int lo = s * SLICE_LEN, hiEnd = min(A_N, lo + SLICE_LEN);
    const u32* keys = keysT + (size_t)c * A_N;
    for (int i = lo + threadIdx.x; i < hiEnd; i += 256) {
        u32 k = keys[i];
        if ((k >> KSH) >= P) {
            int p = atomicAdd(&lcnt, 1);
            if (p < CAND_CAP)
                lbuf[p] = (((u64)(~k)) << 32) | (u32)i;  // asc = score desc, idx asc
        }
    }
    __syncthreads();
    const int n = min(lcnt, CAND_CAP);
    if (threadIdx.x == 0) gbase = (int)atomicAdd(&cnt[c], (u32)n);
    __syncthreads();
    u64* cb = candbuf + (size_t)c * CAND_CAP;
    const int b = gbase;
    for (int i = threadIdx.x; i < n; i += 256) {
        int d = b + i;
        if (d < CAND_CAP) cb[d] = lbuf[i];
    }
}

// ---------------- Stage 3d: per-class bitonic sort + emit top-512 ----------------
__global__ __launch_bounds__(1024)
void sort_emit_kernel(const u64* __restrict__ candbuf, const u32* __restrict__ cnt,
                      const float4* __restrict__ boxes,
                      float4* __restrict__ cand_boxes,
                      float* __restrict__ cand_scores) {
    __shared__ u64 buf[CAND_CAP];   // 16 KB
    const int c = blockIdx.x, tid = threadIdx.x;
    const int n = min((int)cnt[c], CAND_CAP);
    const u64* cb = candbuf + (size_t)c * CAND_CAP;
    for (int i = tid; i < CAND_CAP; i += 1024)
        buf[i] = (i < n) ? cb[i] : ~0ULL;
    __syncthreads();
    for (u32 kk = 2; kk <= CAND_CAP; kk <<= 1) {
        for (u32 j = kk >> 1; j > 0; j >>= 1) {
            for (u32 i = tid; i < CAND_CAP; i += 1024) {
                u32 ixj = i ^ j;
                if (ixj > i) {
                    u64 x = buf[i], y = buf[ixj];
                    bool up = ((i & kk) == 0);
                    if (up ? (x > y) : (x < y)) { buf[i] = y; buf[ixj] = x; }
                }
            }
            __syncthreads();
        }
    }
    if (tid < KCAND) {
        u64 comp = buf[tid];
        u32 idx = (u32)comp;
        u32 key = ~((u32)(comp >> 32));
        cand_scores[c * KCAND + tid] = unfkey(key);
        cand_boxes[c * KCAND + tid] = boxes[idx];
    }
}

// ---------------- Stage 4: IoU bitmask + sequential greedy NMS ----------------
__global__ __launch_bounds__(512)
void nms_kernel(const float4* __restrict__ cand_boxes,
                const float* __restrict__ cand_scores,
                float* __restrict__ kept) {
    __shared__ float4 bx[KCAND];       // 8 KB
    __shared__ float ar[KCAND];        // 2 KB
    __shared__ float sc[KCAND];        // 2 KB
    __shared__ u32 bmask[KCAND * 16];  // 32 KB
    const int c = blockIdx.x, i = threadIdx.x;
    float4 b = cand_boxes[c * KCAND + i];
    bx[i] = b;
    ar[i] = (b.z - b.x) * (b.w - b.y);
    sc[i] = cand_scores[c * KCAND + i];
    __syncthreads();
    const float ai = ar[i];
    u32 m[16];
    #pragma unroll
    for (int w = 0; w < 16; ++w) m[w] = 0;
    // Only j > i bits are consumed by the greedy scan below.
    for (int j = i + 1; j < KCAND; ++j) {
        float4 bj = bx[j];
        float xx1 = fmaxf(b.x, bj.x), yy1 = fmaxf(b.y, bj.y);
        float xx2 = fminf(b.z, bj.z), yy2 = fminf(b.w, bj.w);
        float iw = fmaxf(xx2 - xx1, 0.0f), ih = fmaxf(yy2 - yy1, 0.0f);
        float inter = iw * ih;
        float uni = ai + ar[j] - inter + 1e-8f;
        if (inter > 0.5f * uni) m[j >> 5] |= (1u << (j & 31));
    }
    #pragma unroll
    for (int w = 0; w < 16; ++w) bmask[i * 16 + w] = m[w];
    __syncthreads();
    if (i < 64) {   // wave 0: sequential greedy scan on bitmasks
        u32 removed = 0;   // lane w<16 owns suppressed word w
        for (int t = 0; t < KCAND; ++t) {
            u32 rw = (u32)__shfl((int)removed, t >> 5);
            bool d = (sc[t] > THRESH) && (((rw >> (t & 31)) & 1u) == 0u);
            if (d && i < 16) removed |= bmask[t * 16 + i];
            if (i == 0) kept[c * KCAND + t] = d ? sc[t] : -1.0f;
        }
    }
}

// ---------------- Stage 5: global top-100 + emit detections ----------------
__global__ __launch_bounds__(1024)
void final_kernel(const float* __restrict__ kept,
                  const float4* __restrict__ cand_boxes,
                  float* __restrict__ out) {
    __shared__ u32 hist[NBINS];   // 32 KB
    __shared__ u32 csum[1024];
    __shared__ u64 buf[1024];     // 8 KB
    __shared__ int sP, sN;
    const int tid = threadIdx.x;
    const int TOT = C_N * KCAND;
    for (int i = tid; i < NBINS; i += 1024) hist[i] = 0;
    if (tid == 0) sN = 0;
    __syncthreads();
    for (int i = tid; i < TOT; i += 1024) {
        float s = kept[i];
        if (s > 0.0f) atomicAdd(&hist[fkey(s) >> KSH], 1u);
    }
    __syncthreads();
    {   u32 s = 0; int hi = NBINS - 1 - 8 * tid;
        #pragma unroll
        for (int j = 0; j < 8; ++j) s += hist[hi - j];
        csum[tid] = s;
    }
    __syncthreads();
    if (tid == 0) {
        u32 cum = 0; int P = 0; bool found = false;
        for (int t = 0; t < 1024 && !found; ++t) {
            if (cum + csum[t] >= (u32)MAXDET) {
                int hi = NBINS - 1 - 8 * t;
                for (int j = 0; j < 8; ++j) {
                    u32 h = hist[hi - j];
                    if (cum + h >= (u32)MAXDET) { P = hi - j; found = true; break; }
                    cum += h;
                }
            } else cum += csum[t];
        }
        sP = found ? P : 0;   // P=0 => fewer than 100 kept, take all
    }
    __syncthreads();
    const u32 P = (u32)sP;
    for (int i = tid; i < TOT; i += 1024) {
        float s = kept[i];
        if (s > 0.0f && (fkey(s) >> KSH) >= P) {
            int p = atomicAdd(&sN, 1);
            if (p < 1024)
                buf[p] = (((u64)(~fkey(s))) << 32) | (u32)i;
        }
    }
    __syncthreads();
    int n = min(sN, 1024);
    for (int i = tid; i < 1024; i += 1024) if (i >= n) buf[i] = ~0ULL;
    __syncthreads();
    for (u32 kk = 2; kk <= 1024; kk <<= 1) {
        for (u32 j = kk >> 1; j > 0; j >>= 1) {
            for (u32 i = tid; i < 1024; i += 1024) {
                u32 ixj = i ^ j;
                if (ixj > i) {
                    u64 x = buf[i], y = buf[ixj];
                    bool up = ((i & kk) == 0);
                    if (up ? (x > y) : (x < y)) { buf[i] = y; buf[ixj] = x; }
                }
            }
            __syncthreads();
        }
    }
    if (tid < MAXDET) {
        float row1 = 0, row2 = 0, row3 = 0, row4 = 0, row5 = 0, row6 = 0;
        if (tid < n) {
            u64 comp = buf[tid];
            u32 flat = (u32)comp;
            u32 key = ~((u32)(comp >> 32));
            float s = unfkey(key);
            if (s > 0.0f) {
                float4 b = cand_boxes[flat];
                row1 = b.x; row2 = b.y; row3 = b.z; row4 = b.w;
                row5 = s; row6 = (float)(flat >> 9);   // flat / 512 = class label
            }
        }
        float* o = out + tid * 7;
        o[0] = 0.0f; o[1] = row1; o[2] = row2; o[3] = row3;
        o[4] = row4; o[5] = row5; o[6] = row6;
    }
}

extern "C" void kernel_launch(void* const* d_in, const int* in_sizes, int n_in,
                              void* d_out, int out_size, void* d_ws, size_t ws_size,
                              hipStream_t stream) {
    const float* reg     = (const float*)d_in[1];
    const float* cls     = (const float*)d_in[2];
    const float* anchors = (const float*)d_in[3];
    float* out = (float*)d_out;

    char* ws = (char*)d_ws;
    size_t off = 0;
    auto alloc = [&](size_t bytes) -> void* {
        void* p = ws + off;
        off = (off + bytes + 255) & ~(size_t)255;
        return p;
    };
    u32*    keysT       = (u32*)   alloc((size_t)C_N * A_N * sizeof(u32));     // 39.8 MB
    float4* boxes       = (float4*)alloc((size_t)A_N * sizeof(float4));        // 1.77 MB
    u32*    ghist       = (u32*)   alloc((size_t)C_N * NBINS * sizeof(u32));   // 2.95 MB
    u32*    pivotP      = (u32*)   alloc((size_t)C_N * sizeof(u32));
    u32*    cnt         = (u32*)   alloc((size_t)C_N * sizeof(u32));
    u64*    candbuf     = (u64*)   alloc((size_t)C_N * CAND_CAP * sizeof(u64)); // 1.47 MB
    float4* cand_boxes  = (float4*)alloc((size_t)C_N * KCAND * sizeof(float4));
    float*  cand_scores = (float*) alloc((size_t)C_N * KCAND * sizeof(float));
    float*  kept        = (float*) alloc((size_t)C_N * KCAND * sizeof(float));
    (void)ws_size;

    hipMemsetAsync(ghist, 0, (size_t)C_N * NBINS * sizeof(u32), stream);
    decode_kernel<<<(A_N + 255) / 256, 256, 0, stream>>>(anchors, reg, boxes);
    transpose_kernel<<<(A_N + 63) / 64, 256, 0, stream>>>(cls, keysT);
    hist_kernel<<<C_N * NSLICE, 256, 0, stream>>>(keysT, ghist);
    pivot_kernel<<<C_N, 256, 0, stream>>>(ghist, pivotP, cnt);
    collect_kernel<<<C_N * NSLICE, 256, 0, stream>>>(keysT, pivotP, cnt, candbuf);
    sort_emit_kernel<<<C_N, 1024, 0, stream>>>(candbuf, cnt, boxes, cand_boxes, cand_scores);
    nms_kernel<<<C_N, KCAND, 0, stream>>>(cand_boxes, cand_scores, kept);
    final_kernel<<<1, 1024, 0, stream>>>(kept, cand_boxes, out);
}

// Round 3
// 314.935 us; speedup vs baseline: 1.3187x; 1.2177x over previous
//
#include <hip/hip_runtime.h>
#include <math.h>

// EfficientDet post-processing, device pipeline v3.
// prep(decode+transpose) -> sliced hist -> pivot -> sliced collect ->
// fused sort+NMS (register-pipelined greedy scan, readlane chain) -> top-100.

#define A_N   110484
#define C_N   90
#define KCAND 512
#define NBINS 8192        // 13-bit histogram bins (key >> 19)
#define KSH   19
#define MAXDET 100
#define IMG_F 768.0f
#define THRESH 0.05f
#define NSLICE 8
#define SLICE_LEN ((A_N + NSLICE - 1) / NSLICE)   // 13811
#define CAND_CAP 2048
#define T_BLKS ((A_N + 63) / 64)     // 1727 transpose blocks
#define D_BLKS ((A_N + 255) / 256)   // 432 decode blocks

typedef unsigned int u32;
typedef unsigned long long u64;

__device__ __forceinline__ u32 fkey(float f) {
    u32 u = __float_as_uint(f);
    return (u & 0x80000000u) ? ~u : (u | 0x80000000u);
}
__device__ __forceinline__ float unfkey(u32 k) {
    u32 u = (k & 0x80000000u) ? (k ^ 0x80000000u) : ~k;
    return __uint_as_float(u);
}

// ------- Stage 1: fused decode(boxes) + transpose(sigmoid->key) -------
__global__ __launch_bounds__(256)
void prep_kernel(const float* __restrict__ anchors,
                 const float* __restrict__ reg,
                 const float* __restrict__ cls,
                 float4* __restrict__ boxes,
                 u32* __restrict__ keysT) {
    __shared__ u32 tile[64 * 91];   // 23.3 KB, stride 91 (odd) = conflict-free
    if (blockIdx.x >= T_BLKS) {
        int a = (blockIdx.x - T_BLKS) * 256 + threadIdx.x;
        if (a >= A_N) return;
        float4 an = ((const float4*)anchors)[a];
        float4 dl = ((const float4*)reg)[a];
        float wa = an.z - an.x, ha = an.w - an.y;
        float cx = an.x + 0.5f * wa + dl.x * wa;
        float cy = an.y + 0.5f * ha + dl.y * ha;
        float w = expf(dl.z) * wa;
        float h = expf(dl.w) * ha;
        float4 o;
        o.x = fminf(fmaxf(cx - 0.5f * w, 0.0f), IMG_F);
        o.y = fminf(fmaxf(cy - 0.5f * h, 0.0f), IMG_F);
        o.z = fminf(fmaxf(cx + 0.5f * w, 0.0f), IMG_F);
        o.w = fminf(fmaxf(cy + 0.5f * h, 0.0f), IMG_F);
        boxes[a] = o;
        return;
    }
    int a0 = blockIdx.x * 64;
    int lim = min(64, A_N - a0);
    int cnt = lim * C_N;
    const float* src = cls + (size_t)a0 * C_N;
    for (int i = threadIdx.x; i < cnt; i += 256) {
        float x = src[i];
        float s = 1.0f / (1.0f + expf(-x));
        u32 aa = (u32)i / C_N, c = (u32)i % C_N;
        tile[aa * 91 + c] = fkey(s);
    }
    __syncthreads();
    for (int j = threadIdx.x; j < C_N * 64; j += 256) {
        int c = j >> 6, aa = j & 63;
        if (aa < lim)
            keysT[(size_t)c * A_N + a0 + aa] = tile[aa * 91 + c];
    }
}

// ---------------- Stage 2a: sliced per-class histogram ----------------
__global__ __launch_bounds__(256)
void hist_kernel(const u32* __restrict__ keysT, u32* __restrict__ ghist) {
    __shared__ u32 h[NBINS];   // 32 KB
    const int c = blockIdx.x / NSLICE, s = blockIdx.x % NSLICE;
    for (int i = threadIdx.x; i < NBINS; i += 256) h[i] = 0;
    __syncthreads();
    const int lo = s * SLICE_LEN, hiEnd = min(A_N, lo + SLICE_LEN);
    const u32* keys = keysT + (size_t)c * A_N;
    for (int i = lo + threadIdx.x; i < hiEnd; i += 256)
        atomicAdd(&h[keys[i] >> KSH], 1u);
    __syncthreads();
    u32* gh = ghist + (size_t)c * NBINS;
    for (int i = threadIdx.x; i < NBINS; i += 256) {
        u32 v = h[i];
        if (v) atomicAdd(&gh[i], v);
    }
}

// ---------------- Stage 2b: per-class pivot bin ----------------
__global__ __launch_bounds__(256)
void pivot_kernel(const u32* __restrict__ ghist, u32* __restrict__ pivotP,
                  u32* __restrict__ cnt) {
    __shared__ u32 csum[256];
    const int c = blockIdx.x, tid = threadIdx.x;
    const u32* gh = ghist + (size_t)c * NBINS;
    u32 ssum = 0; const int hi = NBINS - 1 - 32 * tid;
    #pragma unroll 4
    for (int j = 0; j < 32; ++j) ssum += gh[hi - j];
    csum[tid] = ssum;
    __syncthreads();
    if (tid == 0) {
        u32 cum = 0, P = 0; bool found = false;
        for (int t = 0; t < 256 && !found; ++t) {
            if (cum + csum[t] >= (u32)KCAND) {
                int h2 = NBINS - 1 - 32 * t;
                for (int j = 0; j < 32; ++j) {
                    u32 hv = gh[h2 - j];
                    if (cum + hv >= (u32)KCAND) { P = (u32)(h2 - j); found = true; break; }
                    cum += hv;
                }
            } else cum += csum[t];
        }
        pivotP[c] = P;
        cnt[c] = 0;
    }
}

// ---------------- Stage 2c: sliced collect of candidates >= pivot ----------------
__global__ __launch_bounds__(256)
void collect_kernel(const u32* __restrict__ keysT, const u32* __restrict__ pivotP,
                    u32* __restrict__ cnt, u64* __restrict__ candbuf) {
    __shared__ u64 lbuf[CAND_CAP];   // 16 KB
    __shared__ int lcnt, gbase;
    const int c = blockIdx.x / NSLICE, s = blockIdx.x % NSLICE;
    if (threadIdx.x == 0) lcnt = 0;
    __syncthreads();
    const u32 P = pivotP[c];
    const int lo = s * SLICE_LEN, hiEnd = min(A_N, lo + SLICE_LEN);
    const u32* keys = keysT + (size_t)c * A_N;
    for (int i = lo + threadIdx.x; i < hiEnd; i += 256) {
        u32 k = keys[i];
        if ((k >> KSH) >= P) {
            int p = atomicAdd(&lcnt, 1);
            if (p < CAND_CAP)
                lbuf[p] = (((u64)(~k)) << 32) | (u32)i;  // asc = score desc, idx asc
        }
    }
    __syncthreads();
    const int n = min(lcnt, CAND_CAP);
    if (threadIdx.x == 0) gbase = (int)atomicAdd(&cnt[c], (u32)n);
    __syncthreads();
    u64* cb = candbuf + (size_t)c * CAND_CAP;
    const int b = gbase;
    for (int i = threadIdx.x; i < n; i += 256) {
        int d = b + i;
        if (d < CAND_CAP) cb[d] = lbuf[i];
    }
}

// ------ Stage 3: fused per-class sort + IoU mask + greedy NMS scan ------
__global__ __launch_bounds__(1024)
void snms_kernel(const u64* __restrict__ candbuf, const u32* __restrict__ cnt,
                 const float4* __restrict__ boxes,
                 float4* __restrict__ cand_boxes,
                 float* __restrict__ kept) {
    __shared__ u64 buf[CAND_CAP];          // 16 KB
    __shared__ float bxx[KCAND], byy[KCAND], bzz[KCAND], bww[KCAND];  // 8 KB SoA
    __shared__ float ar[KCAND], sc[KCAND]; // 4 KB
    __shared__ u32 bmask[KCAND * 16];      // 32 KB
    __shared__ u32 keepf[16];
    const int c = blockIdx.x, tid = threadIdx.x;

    // --- sort 2048 candidates (asc composite = score desc, idx asc) ---
    const int n = min((int)cnt[c], CAND_CAP);
    const u64* cb = candbuf + (size_t)c * CAND_CAP;
    for (int i = tid; i < CAND_CAP; i += 1024)
        buf[i] = (i < n) ? cb[i] : ~0ULL;
    __syncthreads();
    for (u32 kk = 2; kk <= CAND_CAP; kk <<= 1) {
        for (u32 j = kk >> 1; j > 0; j >>= 1) {
            for (u32 i = tid; i < CAND_CAP; i += 1024) {
                u32 ixj = i ^ j;
                if (ixj > i) {
                    u64 x = buf[i], y = buf[ixj];
                    bool up = ((i & kk) == 0);
                    if (up ? (x > y) : (x < y)) { buf[i] = y; buf[ixj] = x; }
                }
            }
            __syncthreads();
        }
    }
    // --- gather top-512 boxes into SoA; zero mask ---
    if (tid < KCAND) {
        u64 comp = buf[tid];
        u32 idx = (u32)comp;
        u32 key = ~((u32)(comp >> 32));
        float s = unfkey(key);
        sc[tid] = s;
        float4 b = boxes[idx];
        bxx[tid] = b.x; byy[tid] = b.y; bzz[tid] = b.z; bww[tid] = b.w;
        ar[tid] = (b.z - b.x) * (b.w - b.y);
        cand_boxes[c * KCAND + tid] = b;
    }
    for (int i = tid; i < KCAND * 16; i += 1024) bmask[i] = 0;
    if (tid < 16) keepf[tid] = 0;
    __syncthreads();

    // --- upper-triangular IoU mask, 2 threads per row ---
    {
        const int i = tid & (KCAND - 1);
        const int half = tid >> 9;
        const int count = (KCAND - 1) - i;
        const int j0 = i + 1 + (half ? (count >> 1) : 0);
        const int j1 = half ? KCAND : (i + 1 + (count >> 1));
        const float bix = bxx[i], biy = byy[i], biz = bzz[i], biw = bww[i];
        const float ai = ar[i];
        u32 m[16];
        #pragma unroll
        for (int w = 0; w < 16; ++w) m[w] = 0;
        for (int j = j0; j < j1; ++j) {
            float xx1 = fmaxf(bix, bxx[j]), yy1 = fmaxf(biy, byy[j]);
            float xx2 = fminf(biz, bzz[j]), yy2 = fminf(biw, bww[j]);
            float iw = fmaxf(xx2 - xx1, 0.0f), ih = fmaxf(yy2 - yy1, 0.0f);
            float inter = iw * ih;
            float uni = ai + ar[j] - inter + 1e-8f;
            if (inter > 0.5f * uni) m[j >> 5] |= (1u << (j & 31));
        }
        #pragma unroll
        for (int w = 0; w < 16; ++w)
            if (m[w]) atomicOr(&bmask[i * 16 + w], m[w]);
    }
    __syncthreads();

    // --- greedy scan, wave 0; register-pipelined rows + readlane chain ---
    if (tid < 64) {
        const int lw = tid & 15;   // word owned (lanes >=16 mirror lane&15)
        u32 removed = 0, keepw = 0;
        u32 rA[8], rB[8]; float sA[8], sB[8];
        #pragma unroll
        for (int k = 0; k < 8; ++k) { rA[k] = bmask[k * 16 + lw]; sA[k] = sc[k]; }
        #pragma unroll 1
        for (int ch = 0; ch < 64; ch += 2) {
            const int tb1 = (ch + 1) * 8;
            #pragma unroll
            for (int k = 0; k < 8; ++k) { rB[k] = bmask[(tb1 + k) * 16 + lw]; sB[k] = sc[tb1 + k]; }
            {
                const int tb = ch * 8;
                #pragma unroll
                for (int k = 0; k < 8; ++k) {
                    const int t = tb + k;
                    u32 rw = (u32)__builtin_amdgcn_readlane((int)removed, t >> 5);
                    bool d = (sA[k] > THRESH) && (((rw >> (t & 31)) & 1u) == 0u);
                    removed |= d ? rA[k] : 0u;
                    keepw |= (d && (tid == (t >> 5))) ? (1u << (t & 31)) : 0u;
                }
            }
            const int tb2 = (ch + 2 < 64) ? (ch + 2) * 8 : 0;
            #pragma unroll
            for (int k = 0; k < 8; ++k) { rA[k] = bmask[(tb2 + k) * 16 + lw]; sA[k] = sc[tb2 + k]; }
            {
                #pragma unroll
                for (int k = 0; k < 8; ++k) {
                    const int t = tb1 + k;
                    u32 rw = (u32)__builtin_amdgcn_readlane((int)removed, t >> 5);
                    bool d = (sB[k] > THRESH) && (((rw >> (t & 31)) & 1u) == 0u);
                    removed |= d ? rB[k] : 0u;
                    keepw |= (d && (tid == (t >> 5))) ? (1u << (t & 31)) : 0u;
                }
            }
        }
        if (tid < 16) keepf[tid] = keepw;
    }
    __syncthreads();
    if (tid < KCAND) {
        bool k = (keepf[tid >> 5] >> (tid & 31)) & 1u;
        kept[c * KCAND + tid] = k ? sc[tid] : -1.0f;
    }
}

// ---------------- Stage 4: global top-100 + emit detections ----------------
__global__ __launch_bounds__(1024)
void final_kernel(const float* __restrict__ kept,
                  const float4* __restrict__ cand_boxes,
                  float* __restrict__ out) {
    __shared__ u32 hist[NBINS];   // 32 KB
    __shared__ u32 csum[1024];
    __shared__ u64 buf[1024];     // 8 KB
    __shared__ int sP, sN;
    const int tid = threadIdx.x;
    const int TOT = C_N * KCAND;
    for (int i = tid; i < NBINS; i += 1024) hist[i] = 0;
    if (tid == 0) sN = 0;
    __syncthreads();
    for (int i = tid; i < TOT; i += 1024) {
        float s = kept[i];
        if (s > 0.0f) atomicAdd(&hist[fkey(s) >> KSH], 1u);
    }
    __syncthreads();
    {   u32 s = 0; int hi = NBINS - 1 - 8 * tid;
        #pragma unroll
        for (int j = 0; j < 8; ++j) s += hist[hi - j];
        csum[tid] = s;
    }
    __syncthreads();
    if (tid == 0) {
        u32 cum = 0; int P = 0; bool found = false;
        for (int t = 0; t < 1024 && !found; ++t) {
            if (cum + csum[t] >= (u32)MAXDET) {
                int hi = NBINS - 1 - 8 * t;
                for (int j = 0; j < 8; ++j) {
                    u32 h = hist[hi - j];
                    if (cum + h >= (u32)MAXDET) { P = hi - j; found = true; break; }
                    cum += h;
                }
            } else cum += csum[t];
        }
        sP = found ? P : 0;   // P=0 => fewer than 100 kept, take all
    }
    __syncthreads();
    const u32 P = (u32)sP;
    for (int i = tid; i < TOT; i += 1024) {
        float s = kept[i];
        if (s > 0.0f && (fkey(s) >> KSH) >= P) {
            int p = atomicAdd(&sN, 1);
            if (p < 1024)
                buf[p] = (((u64)(~fkey(s))) << 32) | (u32)i;
        }
    }
    __syncthreads();
    int n = min(sN, 1024);
    for (int i = tid; i < 1024; i += 1024) if (i >= n) buf[i] = ~0ULL;
    __syncthreads();
    for (u32 kk = 2; kk <= 1024; kk <<= 1) {
        for (u32 j = kk >> 1; j > 0; j >>= 1) {
            for (u32 i = tid; i < 1024; i += 1024) {
                u32 ixj = i ^ j;
                if (ixj > i) {
                    u64 x = buf[i], y = buf[ixj];
                    bool up = ((i & kk) == 0);
                    if (up ? (x > y) : (x < y)) { buf[i] = y; buf[ixj] = x; }
                }
            }
            __syncthreads();
        }
    }
    if (tid < MAXDET) {
        float row1 = 0, row2 = 0, row3 = 0, row4 = 0, row5 = 0, row6 = 0;
        if (tid < n) {
            u64 comp = buf[tid];
            u32 flat = (u32)comp;
            u32 key = ~((u32)(comp >> 32));
            float s = unfkey(key);
            if (s > 0.0f) {
                float4 b = cand_boxes[flat];
                row1 = b.x; row2 = b.y; row3 = b.z; row4 = b.w;
                row5 = s; row6 = (float)(flat >> 9);   // flat / 512 = class label
            }
        }
        float* o = out + tid * 7;
        o[0] = 0.0f; o[1] = row1; o[2] = row2; o[3] = row3;
        o[4] = row4; o[5] = row5; o[6] = row6;
    }
}

extern "C" void kernel_launch(void* const* d_in, const int* in_sizes, int n_in,
                              void* d_out, int out_size, void* d_ws, size_t ws_size,
                              hipStream_t stream) {
    const float* reg     = (const float*)d_in[1];
    const float* cls     = (const float*)d_in[2];
    const float* anchors = (const float*)d_in[3];
    float* out = (float*)d_out;

    char* ws = (char*)d_ws;
    size_t off = 0;
    auto alloc = [&](size_t bytes) -> void* {
        void* p = ws + off;
        off = (off + bytes + 255) & ~(size_t)255;
        return p;
    };
    u32*    keysT      = (u32*)   alloc((size_t)C_N * A_N * sizeof(u32));      // 39.8 MB
    float4* boxes      = (float4*)alloc((size_t)A_N * sizeof(float4));         // 1.77 MB
    u32*    ghist      = (u32*)   alloc((size_t)C_N * NBINS * sizeof(u32));    // 2.95 MB
    u32*    pivotP     = (u32*)   alloc((size_t)C_N * sizeof(u32));
    u32*    cnt        = (u32*)   alloc((size_t)C_N * sizeof(u32));
    u64*    candbuf    = (u64*)   alloc((size_t)C_N * CAND_CAP * sizeof(u64)); // 1.47 MB
    float4* cand_boxes = (float4*)alloc((size_t)C_N * KCAND * sizeof(float4));
    float*  kept       = (float*) alloc((size_t)C_N * KCAND * sizeof(float));
    (void)ws_size;

    hipMemsetAsync(ghist, 0, (size_t)C_N * NBINS * sizeof(u32), stream);
    prep_kernel<<<T_BLKS + D_BLKS, 256, 0, stream>>>(anchors, reg, cls, boxes, keysT);
    hist_kernel<<<C_N * NSLICE, 256, 0, stream>>>(keysT, ghist);
    pivot_kernel<<<C_N, 256, 0, stream>>>(ghist, pivotP, cnt);
    collect_kernel<<<C_N * NSLICE, 256, 0, stream>>>(keysT, pivotP, cnt, candbuf);
    snms_kernel<<<C_N, 1024, 0, stream>>>(candbuf, cnt, boxes, cand_boxes, kept);
    final_kernel<<<1, 1024, 0, stream>>>(kept, cand_boxes, out);
}

// Round 4
// 282.436 us; speedup vs baseline: 1.4705x; 1.1151x over previous
//
#include <hip/hip_runtime.h>
#include <math.h>

// EfficientDet post-processing, device pipeline v4.
// prep(decode+transpose) -> sliced hist -> pivot(parallel scan) ->
// sliced collect -> fused sort+NMS -> top-100 (parallel scan + sized sort).

#define A_N   110484
#define C_N   90
#define KCAND 512
#define NBINS 8192        // 13-bit histogram bins (key >> 19)
#define KSH   19
#define MAXDET 100
#define IMG_F 768.0f
#define THRESH 0.05f
#define NSLICE 8
#define SLICE_LEN ((A_N + NSLICE - 1) / NSLICE)   // 13811
#define CAND_CAP 2048
#define T_BLKS ((A_N + 63) / 64)     // 1727 transpose blocks
#define D_BLKS ((A_N + 255) / 256)   // 432 decode blocks

typedef unsigned int u32;
typedef unsigned long long u64;

__device__ __forceinline__ u32 fkey(float f) {
    u32 u = __float_as_uint(f);
    return (u & 0x80000000u) ? ~u : (u | 0x80000000u);
}
__device__ __forceinline__ float unfkey(u32 k) {
    u32 u = (k & 0x80000000u) ? (k ^ 0x80000000u) : ~k;
    return __uint_as_float(u);
}

// ------- Stage 1: fused decode(boxes) + transpose(sigmoid->key) -------
__global__ __launch_bounds__(256)
void prep_kernel(const float* __restrict__ anchors,
                 const float* __restrict__ reg,
                 const float* __restrict__ cls,
                 float4* __restrict__ boxes,
                 u32* __restrict__ keysT) {
    __shared__ u32 tile[64 * 91];   // 23.3 KB, stride 91 (odd) = conflict-free
    if (blockIdx.x >= T_BLKS) {
        int a = (blockIdx.x - T_BLKS) * 256 + threadIdx.x;
        if (a >= A_N) return;
        float4 an = ((const float4*)anchors)[a];
        float4 dl = ((const float4*)reg)[a];
        float wa = an.z - an.x, ha = an.w - an.y;
        float cx = an.x + 0.5f * wa + dl.x * wa;
        float cy = an.y + 0.5f * ha + dl.y * ha;
        float w = expf(dl.z) * wa;
        float h = expf(dl.w) * ha;
        float4 o;
        o.x = fminf(fmaxf(cx - 0.5f * w, 0.0f), IMG_F);
        o.y = fminf(fmaxf(cy - 0.5f * h, 0.0f), IMG_F);
        o.z = fminf(fmaxf(cx + 0.5f * w, 0.0f), IMG_F);
        o.w = fminf(fmaxf(cy + 0.5f * h, 0.0f), IMG_F);
        boxes[a] = o;
        return;
    }
    int a0 = blockIdx.x * 64;
    int lim = min(64, A_N - a0);
    int cnt = lim * C_N;
    const float* src = cls + (size_t)a0 * C_N;
    for (int i = threadIdx.x; i < cnt; i += 256) {
        float x = src[i];
        float s = 1.0f / (1.0f + expf(-x));
        u32 aa = (u32)i / C_N, c = (u32)i % C_N;
        tile[aa * 91 + c] = fkey(s);
    }
    __syncthreads();
    for (int j = threadIdx.x; j < C_N * 64; j += 256) {
        int c = j >> 6, aa = j & 63;
        if (aa < lim)
            keysT[(size_t)c * A_N + a0 + aa] = tile[aa * 91 + c];
    }
}

// ---------------- Stage 2a: sliced per-class histogram ----------------
__global__ __launch_bounds__(256)
void hist_kernel(const u32* __restrict__ keysT, u32* __restrict__ ghist) {
    __shared__ u32 h[NBINS];   // 32 KB
    const int c = blockIdx.x / NSLICE, s = blockIdx.x % NSLICE;
    for (int i = threadIdx.x; i < NBINS; i += 256) h[i] = 0;
    __syncthreads();
    const int lo = s * SLICE_LEN, hiEnd = min(A_N, lo + SLICE_LEN);
    const u32* keys = keysT + (size_t)c * A_N;
    for (int i = lo + threadIdx.x; i < hiEnd; i += 256)
        atomicAdd(&h[keys[i] >> KSH], 1u);
    __syncthreads();
    u32* gh = ghist + (size_t)c * NBINS;
    for (int i = threadIdx.x; i < NBINS; i += 256) {
        u32 v = h[i];
        if (v) atomicAdd(&gh[i], v);
    }
}

// ------- Stage 2b: per-class pivot bin (parallel scan, LDS-staged) -------
__global__ __launch_bounds__(256)
void pivot_kernel(const u32* __restrict__ ghist, u32* __restrict__ pivotP,
                  u32* __restrict__ cnt) {
    __shared__ u32 hist[NBINS];   // 32 KB
    __shared__ u32 csum[256];
    __shared__ u32 sP;
    const int c = blockIdx.x, tid = threadIdx.x;
    const u32* gh = ghist + (size_t)c * NBINS;
    for (int i = tid; i < NBINS; i += 256) hist[i] = gh[i];
    if (tid == 0) sP = 0;
    __syncthreads();
    // chunk t covers bins [NBINS-1-32t .. NBINS-32-32t] (descending order)
    u32 own = 0; const int hi = NBINS - 1 - 32 * tid;
    #pragma unroll 4
    for (int j = 0; j < 32; ++j) own += hist[hi - j];
    csum[tid] = own;
    __syncthreads();
    // Hillis-Steele inclusive scan over 256 chunks
    for (int off = 1; off < 256; off <<= 1) {
        u32 v = csum[tid];
        u32 a = (tid >= off) ? csum[tid - off] : 0u;
        __syncthreads();
        csum[tid] = v + a;
        __syncthreads();
    }
    const u32 incl = csum[tid], excl = incl - own;
    if (excl < (u32)KCAND && incl >= (u32)KCAND) {   // unique crossing chunk
        u32 cum = excl;
        for (int j = 0; j < 32; ++j) {
            u32 hv = hist[hi - j];
            if (cum + hv >= (u32)KCAND) { sP = (u32)(hi - j); break; }
            cum += hv;
        }
    }
    __syncthreads();
    if (tid == 0) { pivotP[c] = sP; cnt[c] = 0; }
}

// ---------------- Stage 2c: sliced collect of candidates >= pivot ----------------
__global__ __launch_bounds__(256)
void collect_kernel(const u32* __restrict__ keysT, const u32* __restrict__ pivotP,
                    u32* __restrict__ cnt, u64* __restrict__ candbuf) {
    __shared__ u64 lbuf[CAND_CAP];   // 16 KB
    __shared__ int lcnt, gbase;
    const int c = blockIdx.x / NSLICE, s = blockIdx.x % NSLICE;
    if (threadIdx.x == 0) lcnt = 0;
    __syncthreads();
    const u32 P = pivotP[c];
    const int lo = s * SLICE_LEN, hiEnd = min(A_N, lo + SLICE_LEN);
    const u32* keys = keysT + (size_t)c * A_N;
    for (int i = lo + threadIdx.x; i < hiEnd; i += 256) {
        u32 k = keys[i];
        if ((k >> KSH) >= P) {
            int p = atomicAdd(&lcnt, 1);
            if (p < CAND_CAP)
                lbuf[p] = (((u64)(~k)) << 32) | (u32)i;  // asc = score desc, idx asc
        }
    }
    __syncthreads();
    const int n = min(lcnt, CAND_CAP);
    if (threadIdx.x == 0) gbase = (int)atomicAdd(&cnt[c], (u32)n);
    __syncthreads();
    u64* cb = candbuf + (size_t)c * CAND_CAP;
    const int b = gbase;
    for (int i = threadIdx.x; i < n; i += 256) {
        int d = b + i;
        if (d < CAND_CAP) cb[d] = lbuf[i];
    }
}

// ------ Stage 3: fused per-class sort + IoU mask + greedy NMS scan ------
__global__ __launch_bounds__(1024)
void snms_kernel(const u64* __restrict__ candbuf, const u32* __restrict__ cnt,
                 const float4* __restrict__ boxes,
                 float4* __restrict__ cand_boxes,
                 float* __restrict__ kept) {
    __shared__ u64 buf[CAND_CAP];          // 16 KB
    __shared__ float bxx[KCAND], byy[KCAND], bzz[KCAND], bww[KCAND];  // 8 KB SoA
    __shared__ float ar[KCAND], sc[KCAND]; // 4 KB
    __shared__ u32 bmask[KCAND * 16];      // 32 KB
    __shared__ u32 keepf[16];
    const int c = blockIdx.x, tid = threadIdx.x;

    // --- sort 2048 candidates (asc composite = score desc, idx asc) ---
    const int n = min((int)cnt[c], CAND_CAP);
    const u64* cb = candbuf + (size_t)c * CAND_CAP;
    for (int i = tid; i < CAND_CAP; i += 1024)
        buf[i] = (i < n) ? cb[i] : ~0ULL;
    __syncthreads();
    for (u32 kk = 2; kk <= CAND_CAP; kk <<= 1) {
        for (u32 j = kk >> 1; j > 0; j >>= 1) {
            for (u32 i = tid; i < CAND_CAP; i += 1024) {
                u32 ixj = i ^ j;
                if (ixj > i) {
                    u64 x = buf[i], y = buf[ixj];
                    bool up = ((i & kk) == 0);
                    if (up ? (x > y) : (x < y)) { buf[i] = y; buf[ixj] = x; }
                }
            }
            __syncthreads();
        }
    }
    // --- gather top-512 boxes into SoA; zero mask ---
    if (tid < KCAND) {
        u64 comp = buf[tid];
        u32 idx = (u32)comp;
        u32 key = ~((u32)(comp >> 32));
        float s = unfkey(key);
        sc[tid] = s;
        float4 b = boxes[idx];
        bxx[tid] = b.x; byy[tid] = b.y; bzz[tid] = b.z; bww[tid] = b.w;
        ar[tid] = (b.z - b.x) * (b.w - b.y);
        cand_boxes[c * KCAND + tid] = b;
    }
    for (int i = tid; i < KCAND * 16; i += 1024) bmask[i] = 0;
    if (tid < 16) keepf[tid] = 0;
    __syncthreads();

    // --- upper-triangular IoU mask, 2 threads per row ---
    {
        const int i = tid & (KCAND - 1);
        const int half = tid >> 9;
        const int count = (KCAND - 1) - i;
        const int j0 = i + 1 + (half ? (count >> 1) : 0);
        const int j1 = half ? KCAND : (i + 1 + (count >> 1));
        const float bix = bxx[i], biy = byy[i], biz = bzz[i], biw = bww[i];
        const float ai = ar[i];
        u32 m[16];
        #pragma unroll
        for (int w = 0; w < 16; ++w) m[w] = 0;
        for (int j = j0; j < j1; ++j) {
            float xx1 = fmaxf(bix, bxx[j]), yy1 = fmaxf(biy, byy[j]);
            float xx2 = fminf(biz, bzz[j]), yy2 = fminf(biw, bww[j]);
            float iw = fmaxf(xx2 - xx1, 0.0f), ih = fmaxf(yy2 - yy1, 0.0f);
            float inter = iw * ih;
            float uni = ai + ar[j] - inter + 1e-8f;
            if (inter > 0.5f * uni) m[j >> 5] |= (1u << (j & 31));
        }
        #pragma unroll
        for (int w = 0; w < 16; ++w)
            if (m[w]) atomicOr(&bmask[i * 16 + w], m[w]);
    }
    __syncthreads();

    // --- greedy scan, wave 0; register-pipelined rows + readlane chain ---
    if (tid < 64) {
        const int lw = tid & 15;   // word owned (lanes >=16 mirror lane&15)
        u32 removed = 0, keepw = 0;
        u32 rA[8], rB[8]; float sA[8], sB[8];
        #pragma unroll
        for (int k = 0; k < 8; ++k) { rA[k] = bmask[k * 16 + lw]; sA[k] = sc[k]; }
        #pragma unroll 1
        for (int ch = 0; ch < 64; ch += 2) {
            const int tb1 = (ch + 1) * 8;
            #pragma unroll
            for (int k = 0; k < 8; ++k) { rB[k] = bmask[(tb1 + k) * 16 + lw]; sB[k] = sc[tb1 + k]; }
            {
                const int tb = ch * 8;
                #pragma unroll
                for (int k = 0; k < 8; ++k) {
                    const int t = tb + k;
                    u32 rw = (u32)__builtin_amdgcn_readlane((int)removed, t >> 5);
                    bool d = (sA[k] > THRESH) && (((rw >> (t & 31)) & 1u) == 0u);
                    removed |= d ? rA[k] : 0u;
                    keepw |= (d && (tid == (t >> 5))) ? (1u << (t & 31)) : 0u;
                }
            }
            const int tb2 = (ch + 2 < 64) ? (ch + 2) * 8 : 0;
            #pragma unroll
            for (int k = 0; k < 8; ++k) { rA[k] = bmask[(tb2 + k) * 16 + lw]; sA[k] = sc[tb2 + k]; }
            {
                #pragma unroll
                for (int k = 0; k < 8; ++k) {
                    const int t = tb1 + k;
                    u32 rw = (u32)__builtin_amdgcn_readlane((int)removed, t >> 5);
                    bool d = (sB[k] > THRESH) && (((rw >> (t & 31)) & 1u) == 0u);
                    removed |= d ? rB[k] : 0u;
                    keepw |= (d && (tid == (t >> 5))) ? (1u << (t & 31)) : 0u;
                }
            }
        }
        if (tid < 16) keepf[tid] = keepw;
    }
    __syncthreads();
    if (tid < KCAND) {
        bool k = (keepf[tid >> 5] >> (tid & 31)) & 1u;
        kept[c * KCAND + tid] = k ? sc[tid] : -1.0f;
    }
}

// ------- Stage 4: global top-100 (parallel scan + sized sort) -------
__global__ __launch_bounds__(1024)
void final_kernel(const float* __restrict__ kept,
                  const float4* __restrict__ cand_boxes,
                  float* __restrict__ out) {
    __shared__ u32 hist[NBINS];   // 32 KB
    __shared__ u32 csum[1024];
    __shared__ u64 buf[1024];     // 8 KB
    __shared__ u32 sP;
    __shared__ int sN;
    const int tid = threadIdx.x;
    const int TOT = C_N * KCAND;
    for (int i = tid; i < NBINS; i += 1024) hist[i] = 0;
    if (tid == 0) { sN = 0; sP = 0; }
    __syncthreads();
    for (int i = tid; i < TOT; i += 1024) {
        float s = kept[i];
        if (s > 0.0f) atomicAdd(&hist[fkey(s) >> KSH], 1u);
    }
    __syncthreads();
    // chunk t covers bins [NBINS-1-8t .. NBINS-8-8t] (descending)
    u32 own = 0; const int hi = NBINS - 1 - 8 * tid;
    #pragma unroll
    for (int j = 0; j < 8; ++j) own += hist[hi - j];
    csum[tid] = own;
    __syncthreads();
    for (int off = 1; off < 1024; off <<= 1) {
        u32 v = csum[tid];
        u32 a = (tid >= off) ? csum[tid - off] : 0u;
        __syncthreads();
        csum[tid] = v + a;
        __syncthreads();
    }
    const u32 incl = csum[tid], excl = incl - own;
    if (excl < (u32)MAXDET && incl >= (u32)MAXDET) {
        u32 cum = excl;
        for (int j = 0; j < 8; ++j) {
            u32 h = hist[hi - j];
            if (cum + h >= (u32)MAXDET) { sP = (u32)(hi - j); break; }
            cum += h;
        }
    }
    __syncthreads();
    const u32 P = sP;
    for (int i = tid; i < TOT; i += 1024) {
        float s = kept[i];
        if (s > 0.0f && (fkey(s) >> KSH) >= P) {
            int p = atomicAdd(&sN, 1);
            if (p < 1024)
                buf[p] = (((u64)(~fkey(s))) << 32) | (u32)i;
        }
    }
    __syncthreads();
    const int n = min(sN, 1024);
    u32 m = 128; while ((int)m < n) m <<= 1;   // uniform across block
    for (int i = tid; i < (int)m; i += 1024) if (i >= n) buf[i] = ~0ULL;
    __syncthreads();
    for (u32 kk = 2; kk <= m; kk <<= 1) {
        for (u32 j = kk >> 1; j > 0; j >>= 1) {
            u32 i = (u32)tid;
            if (i < m) {
                u32 ixj = i ^ j;
                if (ixj > i) {
                    u64 x = buf[i], y = buf[ixj];
                    bool up = ((i & kk) == 0);
                    if (up ? (x > y) : (x < y)) { buf[i] = y; buf[ixj] = x; }
                }
            }
            __syncthreads();
        }
    }
    if (tid < MAXDET) {
        float row1 = 0, row2 = 0, row3 = 0, row4 = 0, row5 = 0, row6 = 0;
        if (tid < n) {
            u64 comp = buf[tid];
            u32 flat = (u32)comp;
            u32 key = ~((u32)(comp >> 32));
            float s = unfkey(key);
            if (s > 0.0f) {
                float4 b = cand_boxes[flat];
                row1 = b.x; row2 = b.y; row3 = b.z; row4 = b.w;
                row5 = s; row6 = (float)(flat >> 9);   // flat / 512 = class label
            }
        }
        float* o = out + tid * 7;
        o[0] = 0.0f; o[1] = row1; o[2] = row2; o[3] = row3;
        o[4] = row4; o[5] = row5; o[6] = row6;
    }
}

extern "C" void kernel_launch(void* const* d_in, const int* in_sizes, int n_in,
                              void* d_out, int out_size, void* d_ws, size_t ws_size,
                              hipStream_t stream) {
    const float* reg     = (const float*)d_in[1];
    const float* cls     = (const float*)d_in[2];
    const float* anchors = (const float*)d_in[3];
    float* out = (float*)d_out;

    char* ws = (char*)d_ws;
    size_t off = 0;
    auto alloc = [&](size_t bytes) -> void* {
        void* p = ws + off;
        off = (off + bytes + 255) & ~(size_t)255;
        return p;
    };
    u32*    keysT      = (u32*)   alloc((size_t)C_N * A_N * sizeof(u32));      // 39.8 MB
    float4* boxes      = (float4*)alloc((size_t)A_N * sizeof(float4));         // 1.77 MB
    u32*    ghist      = (u32*)   alloc((size_t)C_N * NBINS * sizeof(u32));    // 2.95 MB
    u32*    pivotP     = (u32*)   alloc((size_t)C_N * sizeof(u32));
    u32*    cnt        = (u32*)   alloc((size_t)C_N * sizeof(u32));
    u64*    candbuf    = (u64*)   alloc((size_t)C_N * CAND_CAP * sizeof(u64)); // 1.47 MB
    float4* cand_boxes = (float4*)alloc((size_t)C_N * KCAND * sizeof(float4));
    float*  kept       = (float*) alloc((size_t)C_N * KCAND * sizeof(float));
    (void)ws_size;

    hipMemsetAsync(ghist, 0, (size_t)C_N * NBINS * sizeof(u32), stream);
    prep_kernel<<<T_BLKS + D_BLKS, 256, 0, stream>>>(anchors, reg, cls, boxes, keysT);
    hist_kernel<<<C_N * NSLICE, 256, 0, stream>>>(keysT, ghist);
    pivot_kernel<<<C_N, 256, 0, stream>>>(ghist, pivotP, cnt);
    collect_kernel<<<C_N * NSLICE, 256, 0, stream>>>(keysT, pivotP, cnt, candbuf);
    snms_kernel<<<C_N, 1024, 0, stream>>>(candbuf, cnt, boxes, cand_boxes, kept);
    final_kernel<<<1, 1024, 0, stream>>>(kept, cand_boxes, out);
}

// Round 5
// 248.262 us; speedup vs baseline: 1.6729x; 1.1377x over previous
//
#include <hip/hip_runtime.h>
#include <math.h>

// EfficientDet post-processing, device pipeline v5.
// prep(decode+transpose) -> sliced hist(vec4) -> pivot(parallel scan) ->
// sliced collect(vec4) -> fused hybrid-sort+NMS (shuffle bitonic, ~10 barriers)
// -> top-100 (parallel scan + sized sort).

#define A_N   110484
#define C_N   90
#define KCAND 512
#define NBINS 8192        // 13-bit histogram bins (key >> 19)
#define KSH   19
#define MAXDET 100
#define IMG_F 768.0f
#define THRESH 0.05f
#define NSLICE 8
#define VTOT   (A_N / 4)                          // 27621 (A_N divisible by 4)
#define VSLICE ((VTOT + NSLICE - 1) / NSLICE)     // 3453
#define CAND_CAP 2048
#define T_BLKS ((A_N + 63) / 64)     // 1727 transpose blocks
#define D_BLKS ((A_N + 255) / 256)   // 432 decode blocks

typedef unsigned int u32;
typedef unsigned long long u64;

__device__ __forceinline__ u32 fkey(float f) {
    u32 u = __float_as_uint(f);
    return (u & 0x80000000u) ? ~u : (u | 0x80000000u);
}
__device__ __forceinline__ float unfkey(u32 k) {
    u32 u = (k & 0x80000000u) ? (k ^ 0x80000000u) : ~k;
    return __uint_as_float(u);
}
__device__ __forceinline__ u64 shflx64(u64 v, int m) {
    u32 lo = (u32)__shfl_xor((int)(u32)v, m, 64);
    u32 hi = (u32)__shfl_xor((int)(v >> 32), m, 64);
    return ((u64)hi << 32) | lo;
}

// ------- Stage 1: fused decode(boxes) + transpose(sigmoid->key) -------
__global__ __launch_bounds__(256)
void prep_kernel(const float* __restrict__ anchors,
                 const float* __restrict__ reg,
                 const float* __restrict__ cls,
                 float4* __restrict__ boxes,
                 u32* __restrict__ keysT) {
    __shared__ u32 tile[64 * 91];   // 23.3 KB, stride 91 (odd) = conflict-free
    if (blockIdx.x >= T_BLKS) {
        int a = (blockIdx.x - T_BLKS) * 256 + threadIdx.x;
        if (a >= A_N) return;
        float4 an = ((const float4*)anchors)[a];
        float4 dl = ((const float4*)reg)[a];
        float wa = an.z - an.x, ha = an.w - an.y;
        float cx = an.x + 0.5f * wa + dl.x * wa;
        float cy = an.y + 0.5f * ha + dl.y * ha;
        float w = expf(dl.z) * wa;
        float h = expf(dl.w) * ha;
        float4 o;
        o.x = fminf(fmaxf(cx - 0.5f * w, 0.0f), IMG_F);
        o.y = fminf(fmaxf(cy - 0.5f * h, 0.0f), IMG_F);
        o.z = fminf(fmaxf(cx + 0.5f * w, 0.0f), IMG_F);
        o.w = fminf(fmaxf(cy + 0.5f * h, 0.0f), IMG_F);
        boxes[a] = o;
        return;
    }
    int a0 = blockIdx.x * 64;
    int lim = min(64, A_N - a0);
    int cnt = lim * C_N;
    const float* src = cls + (size_t)a0 * C_N;
    for (int i = threadIdx.x; i < cnt; i += 256) {
        float x = src[i];
        float s = 1.0f / (1.0f + expf(-x));
        u32 aa = (u32)i / C_N, c = (u32)i % C_N;
        tile[aa * 91 + c] = fkey(s);
    }
    __syncthreads();
    for (int j = threadIdx.x; j < C_N * 64; j += 256) {
        int c = j >> 6, aa = j & 63;
        if (aa < lim)
            keysT[(size_t)c * A_N + a0 + aa] = tile[aa * 91 + c];
    }
}

// ---------------- Stage 2a: sliced per-class histogram (vec4) ----------------
__global__ __launch_bounds__(256)
void hist_kernel(const u32* __restrict__ keysT, u32* __restrict__ ghist) {
    __shared__ u32 h[NBINS];   // 32 KB
    const int c = blockIdx.x / NSLICE, s = blockIdx.x % NSLICE;
    for (int i = threadIdx.x; i < NBINS; i += 256) h[i] = 0;
    __syncthreads();
    const int lo = s * VSLICE, hiEnd = min(VTOT, lo + VSLICE);
    const uint4* kv = (const uint4*)(keysT + (size_t)c * A_N);
    for (int i = lo + threadIdx.x; i < hiEnd; i += 256) {
        uint4 k = kv[i];
        atomicAdd(&h[k.x >> KSH], 1u);
        atomicAdd(&h[k.y >> KSH], 1u);
        atomicAdd(&h[k.z >> KSH], 1u);
        atomicAdd(&h[k.w >> KSH], 1u);
    }
    __syncthreads();
    u32* gh = ghist + (size_t)c * NBINS;
    for (int i = threadIdx.x; i < NBINS; i += 256) {
        u32 v = h[i];
        if (v) atomicAdd(&gh[i], v);
    }
}

// ------- Stage 2b: per-class pivot bin (parallel scan, LDS-staged) -------
__global__ __launch_bounds__(256)
void pivot_kernel(const u32* __restrict__ ghist, u32* __restrict__ pivotP,
                  u32* __restrict__ cnt) {
    __shared__ u32 hist[NBINS];   // 32 KB
    __shared__ u32 csum[256];
    __shared__ u32 sP;
    const int c = blockIdx.x, tid = threadIdx.x;
    const u32* gh = ghist + (size_t)c * NBINS;
    for (int i = tid; i < NBINS; i += 256) hist[i] = gh[i];
    if (tid == 0) sP = 0;
    __syncthreads();
    u32 own = 0; const int hi = NBINS - 1 - 32 * tid;
    #pragma unroll 4
    for (int j = 0; j < 32; ++j) own += hist[hi - j];
    csum[tid] = own;
    __syncthreads();
    for (int off = 1; off < 256; off <<= 1) {
        u32 v = csum[tid];
        u32 a = (tid >= off) ? csum[tid - off] : 0u;
        __syncthreads();
        csum[tid] = v + a;
        __syncthreads();
    }
    const u32 incl = csum[tid], excl = incl - own;
    if (excl < (u32)KCAND && incl >= (u32)KCAND) {   // unique crossing chunk
        u32 cum = excl;
        for (int j = 0; j < 32; ++j) {
            u32 hv = hist[hi - j];
            if (cum + hv >= (u32)KCAND) { sP = (u32)(hi - j); break; }
            cum += hv;
        }
    }
    __syncthreads();
    if (tid == 0) { pivotP[c] = sP; cnt[c] = 0; }
}

// -------- Stage 2c: sliced collect of candidates >= pivot (vec4) --------
__global__ __launch_bounds__(256)
void collect_kernel(const u32* __restrict__ keysT, const u32* __restrict__ pivotP,
                    u32* __restrict__ cnt, u64* __restrict__ candbuf) {
    __shared__ u64 lbuf[CAND_CAP];   // 16 KB
    __shared__ int lcnt, gbase;
    const int c = blockIdx.x / NSLICE, s = blockIdx.x % NSLICE;
    if (threadIdx.x == 0) lcnt = 0;
    __syncthreads();
    const u32 P = pivotP[c];
    const int lo = s * VSLICE, hiEnd = min(VTOT, lo + VSLICE);
    const uint4* kv = (const uint4*)(keysT + (size_t)c * A_N);
    for (int i = lo + threadIdx.x; i < hiEnd; i += 256) {
        uint4 k = kv[i];
        u32 base = (u32)(4 * i);
        if ((k.x >> KSH) >= P) {
            int p = atomicAdd(&lcnt, 1);
            if (p < CAND_CAP) lbuf[p] = (((u64)(~k.x)) << 32) | base;
        }
        if ((k.y >> KSH) >= P) {
            int p = atomicAdd(&lcnt, 1);
            if (p < CAND_CAP) lbuf[p] = (((u64)(~k.y)) << 32) | (base + 1);
        }
        if ((k.z >> KSH) >= P) {
            int p = atomicAdd(&lcnt, 1);
            if (p < CAND_CAP) lbuf[p] = (((u64)(~k.z)) << 32) | (base + 2);
        }
        if ((k.w >> KSH) >= P) {
            int p = atomicAdd(&lcnt, 1);
            if (p < CAND_CAP) lbuf[p] = (((u64)(~k.w)) << 32) | (base + 3);
        }
    }
    __syncthreads();
    const int n = min(lcnt, CAND_CAP);
    if (threadIdx.x == 0) gbase = (int)atomicAdd(&cnt[c], (u32)n);
    __syncthreads();
    u64* cb = candbuf + (size_t)c * CAND_CAP;
    const int b = gbase;
    for (int i = threadIdx.x; i < n; i += 256) {
        int d = b + i;
        if (d < CAND_CAP) cb[d] = lbuf[i];
    }
}

// ------ Stage 3: fused hybrid-bitonic sort + IoU mask + greedy NMS scan ------
// Element x = 128*wave + 64*reg + lane; j<=32 via shuffle, j==64 in-lane,
// j>=128 via ping-pong LDS (one barrier each, ~10 total).
__global__ __launch_bounds__(1024)
void snms_kernel(const u64* __restrict__ candbuf, const u32* __restrict__ cnt,
                 const float4* __restrict__ boxes,
                 float4* __restrict__ cand_boxes,
                 float* __restrict__ kept) {
    __shared__ u64 sortbuf[2][CAND_CAP];   // 32 KB, reused as bmask after sort
    __shared__ float bxx[KCAND], byy[KCAND], bzz[KCAND], bww[KCAND];
    __shared__ float ar[KCAND], sc[KCAND];
    __shared__ u32 keepf[16];
    u32* bmask = (u32*)&sortbuf[0][0];     // 512 rows x 16 words = 32 KB
    const int c = blockIdx.x, tid = threadIdx.x;
    const int l = tid & 63, w = tid >> 6;
    const int i0 = 128 * w + l, i1 = i0 + 64;

    const int n = min((int)cnt[c], CAND_CAP);
    const u64* cb = candbuf + (size_t)c * CAND_CAP;
    u64 v0 = (i0 < n) ? cb[i0] : ~0ULL;
    u64 v1 = (i1 < n) ? cb[i1] : ~0ULL;

    int p = 0;
    #pragma unroll
    for (u32 kk = 2; kk <= CAND_CAP; kk <<= 1) {
        #pragma unroll
        for (u32 j = kk >> 1; j > 0; j >>= 1) {
            if (j >= 128) {
                sortbuf[p][i0] = v0; sortbuf[p][i1] = v1;
                __syncthreads();
                u64 w0 = sortbuf[p][i0 ^ j], w1 = sortbuf[p][i1 ^ j];
                bool m0 = (((i0 & j) == 0) == ((i0 & kk) == 0));
                bool m1 = (((i1 & j) == 0) == ((i1 & kk) == 0));
                v0 = m0 ? (v0 < w0 ? v0 : w0) : (v0 > w0 ? v0 : w0);
                v1 = m1 ? (v1 < w1 ? v1 : w1) : (v1 > w1 ? v1 : w1);
                p ^= 1;
            } else if (j == 64) {
                bool up = ((i0 & kk) == 0);
                u64 mn = v0 < v1 ? v0 : v1, mx = v0 < v1 ? v1 : v0;
                v0 = up ? mn : mx; v1 = up ? mx : mn;
            } else {
                u64 w0 = shflx64(v0, (int)j), w1 = shflx64(v1, (int)j);
                bool m0 = (((i0 & j) == 0) == ((i0 & kk) == 0));
                bool m1 = (((i1 & j) == 0) == ((i1 & kk) == 0));
                v0 = m0 ? (v0 < w0 ? v0 : w0) : (v0 > w0 ? v0 : w0);
                v1 = m1 ? (v1 < w1 ? v1 : w1) : (v1 > w1 ? v1 : w1);
            }
        }
    }
    __syncthreads();   // sort done (values in registers); sortbuf free

    // --- top-512 -> SoA + cand_boxes; zero mask ---
    if (w < 4) {   // i0,i1 < 512
        u32 idx0 = (u32)v0, key0 = ~((u32)(v0 >> 32));
        u32 idx1 = (u32)v1, key1 = ~((u32)(v1 >> 32));
        float s0 = unfkey(key0), s1 = unfkey(key1);
        sc[i0] = s0; sc[i1] = s1;
        float4 b0 = boxes[idx0], b1 = boxes[idx1];
        bxx[i0] = b0.x; byy[i0] = b0.y; bzz[i0] = b0.z; bww[i0] = b0.w;
        bxx[i1] = b1.x; byy[i1] = b1.y; bzz[i1] = b1.z; bww[i1] = b1.w;
        ar[i0] = (b0.z - b0.x) * (b0.w - b0.y);
        ar[i1] = (b1.z - b1.x) * (b1.w - b1.y);
        cand_boxes[c * KCAND + i0] = b0;
        cand_boxes[c * KCAND + i1] = b1;
    }
    for (int i = tid; i < KCAND * 16; i += 1024) bmask[i] = 0;
    if (tid < 16) keepf[tid] = 0;
    __syncthreads();

    // --- upper-triangular IoU mask, 2 threads per row ---
    {
        const int i = tid & (KCAND - 1);
        const int half = tid >> 9;
        const int count = (KCAND - 1) - i;
        const int j0 = i + 1 + (half ? (count >> 1) : 0);
        const int j1 = half ? KCAND : (i + 1 + (count >> 1));
        const float bix = bxx[i], biy = byy[i], biz = bzz[i], biw = bww[i];
        const float ai = ar[i];
        u32 m[16];
        #pragma unroll
        for (int q = 0; q < 16; ++q) m[q] = 0;
        for (int j = j0; j < j1; ++j) {
            float xx1 = fmaxf(bix, bxx[j]), yy1 = fmaxf(biy, byy[j]);
            float xx2 = fminf(biz, bzz[j]), yy2 = fminf(biw, bww[j]);
            float iw = fmaxf(xx2 - xx1, 0.0f), ih = fmaxf(yy2 - yy1, 0.0f);
            float inter = iw * ih;
            float uni = ai + ar[j] - inter + 1e-8f;
            if (inter > 0.5f * uni) m[j >> 5] |= (1u << (j & 31));
        }
        #pragma unroll
        for (int q = 0; q < 16; ++q)
            if (m[q]) atomicOr(&bmask[i * 16 + q], m[q]);
    }
    __syncthreads();

    // --- greedy scan, wave 0; register-pipelined rows + readlane chain ---
    if (tid < 64) {
        const int lw = tid & 15;
        u32 removed = 0, keepw = 0;
        u32 rA[8], rB[8]; float sA[8], sB[8];
        #pragma unroll
        for (int k = 0; k < 8; ++k) { rA[k] = bmask[k * 16 + lw]; sA[k] = sc[k]; }
        #pragma unroll 1
        for (int ch = 0; ch < 64; ch += 2) {
            const int tb1 = (ch + 1) * 8;
            #pragma unroll
            for (int k = 0; k < 8; ++k) { rB[k] = bmask[(tb1 + k) * 16 + lw]; sB[k] = sc[tb1 + k]; }
            {
                const int tb = ch * 8;
                #pragma unroll
                for (int k = 0; k < 8; ++k) {
                    const int t = tb + k;
                    u32 rw = (u32)__builtin_amdgcn_readlane((int)removed, t >> 5);
                    bool d = (sA[k] > THRESH) && (((rw >> (t & 31)) & 1u) == 0u);
                    removed |= d ? rA[k] : 0u;
                    keepw |= (d && (tid == (t >> 5))) ? (1u << (t & 31)) : 0u;
                }
            }
            const int tb2 = (ch + 2 < 64) ? (ch + 2) * 8 : 0;
            #pragma unroll
            for (int k = 0; k < 8; ++k) { rA[k] = bmask[(tb2 + k) * 16 + lw]; sA[k] = sc[tb2 + k]; }
            {
                #pragma unroll
                for (int k = 0; k < 8; ++k) {
                    const int t = tb1 + k;
                    u32 rw = (u32)__builtin_amdgcn_readlane((int)removed, t >> 5);
                    bool d = (sB[k] > THRESH) && (((rw >> (t & 31)) & 1u) == 0u);
                    removed |= d ? rB[k] : 0u;
                    keepw |= (d && (tid == (t >> 5))) ? (1u << (t & 31)) : 0u;
                }
            }
        }
        if (tid < 16) keepf[tid] = keepw;
    }
    __syncthreads();
    if (tid < KCAND) {
        bool k = (keepf[tid >> 5] >> (tid & 31)) & 1u;
        kept[c * KCAND + tid] = k ? sc[tid] : -1.0f;
    }
}

// ------- Stage 4: global top-100 (parallel scan + sized sort) -------
__global__ __launch_bounds__(1024)
void final_kernel(const float* __restrict__ kept,
                  const float4* __restrict__ cand_boxes,
                  float* __restrict__ out) {
    __shared__ u32 hist[NBINS];   // 32 KB
    __shared__ u32 csum[1024];
    __shared__ u64 buf[1024];     // 8 KB
    __shared__ u32 sP;
    __shared__ int sN;
    const int tid = threadIdx.x;
    const int TOT = C_N * KCAND;
    for (int i = tid; i < NBINS; i += 1024) hist[i] = 0;
    if (tid == 0) { sN = 0; sP = 0; }
    __syncthreads();
    for (int i = tid; i < TOT; i += 1024) {
        float s = kept[i];
        if (s > 0.0f) atomicAdd(&hist[fkey(s) >> KSH], 1u);
    }
    __syncthreads();
    u32 own = 0; const int hi = NBINS - 1 - 8 * tid;
    #pragma unroll
    for (int j = 0; j < 8; ++j) own += hist[hi - j];
    csum[tid] = own;
    __syncthreads();
    for (int off = 1; off < 1024; off <<= 1) {
        u32 v = csum[tid];
        u32 a = (tid >= off) ? csum[tid - off] : 0u;
        __syncthreads();
        csum[tid] = v + a;
        __syncthreads();
    }
    const u32 incl = csum[tid], excl = incl - own;
    if (excl < (u32)MAXDET && incl >= (u32)MAXDET) {
        u32 cum = excl;
        for (int j = 0; j < 8; ++j) {
            u32 h = hist[hi - j];
            if (cum + h >= (u32)MAXDET) { sP = (u32)(hi - j); break; }
            cum += h;
        }
    }
    __syncthreads();
    const u32 P = sP;
    for (int i = tid; i < TOT; i += 1024) {
        float s = kept[i];
        if (s > 0.0f && (fkey(s) >> KSH) >= P) {
            int p = atomicAdd(&sN, 1);
            if (p < 1024)
                buf[p] = (((u64)(~fkey(s))) << 32) | (u32)i;
        }
    }
    __syncthreads();
    const int n = min(sN, 1024);
    u32 m = 128; while ((int)m < n) m <<= 1;   // uniform across block
    for (int i = tid; i < (int)m; i += 1024) if (i >= n) buf[i] = ~0ULL;
    __syncthreads();
    for (u32 kk = 2; kk <= m; kk <<= 1) {
        for (u32 j = kk >> 1; j > 0; j >>= 1) {
            u32 i = (u32)tid;
            if (i < m) {
                u32 ixj = i ^ j;
                if (ixj > i) {
                    u64 x = buf[i], y = buf[ixj];
                    bool up = ((i & kk) == 0);
                    if (up ? (x > y) : (x < y)) { buf[i] = y; buf[ixj] = x; }
                }
            }
            __syncthreads();
        }
    }
    if (tid < MAXDET) {
        float row1 = 0, row2 = 0, row3 = 0, row4 = 0, row5 = 0, row6 = 0;
        if (tid < n) {
            u64 comp = buf[tid];
            u32 flat = (u32)comp;
            u32 key = ~((u32)(comp >> 32));
            float s = unfkey(key);
            if (s > 0.0f) {
                float4 b = cand_boxes[flat];
                row1 = b.x; row2 = b.y; row3 = b.z; row4 = b.w;
                row5 = s; row6 = (float)(flat >> 9);   // flat / 512 = class label
            }
        }
        float* o = out + tid * 7;
        o[0] = 0.0f; o[1] = row1; o[2] = row2; o[3] = row3;
        o[4] = row4; o[5] = row5; o[6] = row6;
    }
}

extern "C" void kernel_launch(void* const* d_in, const int* in_sizes, int n_in,
                              void* d_out, int out_size, void* d_ws, size_t ws_size,
                              hipStream_t stream) {
    const float* reg     = (const float*)d_in[1];
    const float* cls     = (const float*)d_in[2];
    const float* anchors = (const float*)d_in[3];
    float* out = (float*)d_out;

    char* ws = (char*)d_ws;
    size_t off = 0;
    auto alloc = [&](size_t bytes) -> void* {
        void* p = ws + off;
        off = (off + bytes + 255) & ~(size_t)255;
        return p;
    };
    u32*    keysT      = (u32*)   alloc((size_t)C_N * A_N * sizeof(u32));      // 39.8 MB
    float4* boxes      = (float4*)alloc((size_t)A_N * sizeof(float4));         // 1.77 MB
    u32*    ghist      = (u32*)   alloc((size_t)C_N * NBINS * sizeof(u32));    // 2.95 MB
    u32*    pivotP     = (u32*)   alloc((size_t)C_N * sizeof(u32));
    u32*    cnt        = (u32*)   alloc((size_t)C_N * sizeof(u32));
    u64*    candbuf    = (u64*)   alloc((size_t)C_N * CAND_CAP * sizeof(u64)); // 1.47 MB
    float4* cand_boxes = (float4*)alloc((size_t)C_N * KCAND * sizeof(float4));
    float*  kept       = (float*) alloc((size_t)C_N * KCAND * sizeof(float));
    (void)ws_size;

    hipMemsetAsync(ghist, 0, (size_t)C_N * NBINS * sizeof(u32), stream);
    prep_kernel<<<T_BLKS + D_BLKS, 256, 0, stream>>>(anchors, reg, cls, boxes, keysT);
    hist_kernel<<<C_N * NSLICE, 256, 0, stream>>>(keysT, ghist);
    pivot_kernel<<<C_N, 256, 0, stream>>>(ghist, pivotP, cnt);
    collect_kernel<<<C_N * NSLICE, 256, 0, stream>>>(keysT, pivotP, cnt, candbuf);
    snms_kernel<<<C_N, 1024, 0, stream>>>(candbuf, cnt, boxes, cand_boxes, kept);
    final_kernel<<<1, 1024, 0, stream>>>(kept, cand_boxes, out);
}